// Round 5
// baseline (103.196 us; speedup 1.0000x reference)
//
#include <hip/hip_runtime.h>

// Problem shape (fixed by reference setup_inputs):
//   bert_emb:    [B=4, Lp=256, D=768] fp32
//   pieces2word: [B=4, Lw=200, Lp=256] int32 (0/1)
//   out:         [B=4, Lw=200, D=768] fp32
// out[b,w,d] = max over {p : mask[b,w,p]!=0} of emb[b,p,d], else global min(emb).
//
// R15 — W=10 reuse at UNCHANGED occupancy (fix of R14's failure mode).
//  R14 lesson: W=10 @512thr halved wave count -> latency exposure cost ~4us,
//  swamping the ~1.8us L2 saving. Wave count = B*CHUNKS*(256/PPS)*(200/W);
//  keep it at 3840 by PPS 32->16 alongside W 5->10:
//    240 blocks x 1024 threads (16 waves). Wave s owns pieces [16s,16s+16)
//    for all 10 words. Per-wave VALU (960) / SALU (320) identical to R13.
//    16 waves/CU on 240 CUs (4/SIMD) = R13's residency; per-CU emb stream
//    HALVED (256KB vs 512KB) with no duplicate loads -> L2 123 -> 61 MB.
//  Merge: 16 segments x 10 words = 160KB acc state -> staged tree in
//  DISJOINT dynamic-LDS regions (150.6KB total, 2 barriers):
//    phase0: waves 4..15 write acc -> r1[s-4]   (120KB)
//    phase1: waves 0..3 fold r1[s], r1[s+4], r1[s+8] into acc;
//            non-owner waves write acc -> r2 slots (30KB)
//    phase2: wave 0 finalizes words 0-4, wave 1 words 5-9 (fold 3 r2 slots),
//            om-check, float4 stores.
//  Keeps R12/R13 v_max3 pair-merge (1.5 VALU/elem) + float4 gating (one VCC
//  per mask bit covers 4 cndmasks). acc init = -inf bit-exact; empty-mask
//  word (never for fixed inputs) -> global-min fallback.

#define B_  4
#define LP_ 256
#define LW_ 200
#define D_  768
#define D4_ (D_ / 4)              // 192 float4 per row
#define CHUNKS 3                  // 3 chunks x 256 floats (1 float4 per lane)
#define W_  10                    // words per block
#define WG_ (LW_ / W_)            // 20 word-groups
#define NBLK (B_ * CHUNKS * WG_)  // 240 blocks
#define SEGS 16                   // waves (piece segments) per block
#define PPS 16                    // pieces per segment

// Dynamic LDS: r1[12][W_][64] float4 | r2[3][W_][64] float4 | smask[SEGS][W_]
#define R1_BYTES (12 * W_ * 64 * 16)
#define R2_BYTES (3 * W_ * 64 * 16)
#define SMEM_BYTES (R1_BYTES + R2_BYTES + SEGS * W_ * 4)

__device__ __forceinline__ void max3_inplace(float& d, float a, float b) {
    asm("v_max3_f32 %0, %1, %2, %3" : "=v"(d) : "v"(d), "v"(a), "v"(b));
}

__global__ __launch_bounds__(1024) void word_max_scan(
    const float* __restrict__ emb, const int* __restrict__ p2w,
    float* __restrict__ out)
{
    extern __shared__ char smem[];
    float4 (*r1)[W_][64] = reinterpret_cast<float4 (*)[W_][64]>(smem);
    float4 (*r2)[W_][64] =
        reinterpret_cast<float4 (*)[W_][64]>(smem + R1_BYTES);
    unsigned int (*smask)[W_] =
        reinterpret_cast<unsigned int (*)[W_]>(smem + R1_BYTES + R2_BYTES);

    const int blk   = blockIdx.x;
    const int wg    = blk % WG_;
    const int rest  = blk / WG_;
    const int chunk = rest % CHUNKS;
    const int b     = rest / CHUNKS;
    const int lane  = threadIdx.x & 63;
    const int s     = threadIdx.x >> 6;     // piece segment 0..15
    const int w0    = wg * W_;

    // Each wave ballots a 16-bit mask for its 16 pieces, per word.
    unsigned int m[W_];
    const int pc = s * PPS + (lane & 15);
    #pragma unroll
    for (int j = 0; j < W_; ++j) {
        const int* mrow = p2w + (b * LW_ + w0 + j) * LP_;
        m[j] = (unsigned int)__ballot((lane < 16) && (mrow[pc] != 0));
    }

    const float ninf = __uint_as_float(0xFF800000u);
    float4 acc[W_];
    #pragma unroll
    for (int j = 0; j < W_; ++j) acc[j] = make_float4(ninf, ninf, ninf, ninf);

    // Wave's row stream: rows [16s, 16s+16), column = chunk*64 + lane (float4).
    const float4* rps = (const float4*)(emb + (size_t)b * LP_ * D_)
                        + chunk * 64 + lane + (size_t)(s * PPS) * D4_;

    #pragma unroll
    for (int g = 0; g < PPS; g += 8) {
        float4 v[8];
        #pragma unroll
        for (int k = 0; k < 8; ++k)
            v[k] = rps[(size_t)(g + k) * D4_];
        #pragma unroll
        for (int k = 0; k < 8; k += 2) {
            #pragma unroll
            for (int j = 0; j < W_; ++j) {
                const bool b0 = (m[j] >> (g + k))     & 1u;  // uniform
                const bool b1 = (m[j] >> (g + k + 1)) & 1u;  // uniform
                // One VCC per bit gates FOUR cndmasks (amortized SALU).
                float sx0 = b0 ? v[k].x     : ninf;
                float sy0 = b0 ? v[k].y     : ninf;
                float sz0 = b0 ? v[k].z     : ninf;
                float sw0 = b0 ? v[k].w     : ninf;
                float sx1 = b1 ? v[k + 1].x : ninf;
                float sy1 = b1 ? v[k + 1].y : ninf;
                float sz1 = b1 ? v[k + 1].z : ninf;
                float sw1 = b1 ? v[k + 1].w : ninf;
                max3_inplace(acc[j].x, sx0, sx1);
                max3_inplace(acc[j].y, sy0, sy1);
                max3_inplace(acc[j].z, sz0, sz1);
                max3_inplace(acc[j].w, sw0, sw1);
            }
        }
    }

    // ---- Staged merge of 16 segments, 2 barriers, disjoint regions ----
    // Phase 0: waves 4..15 publish; everyone publishes masks.
    if (s >= 4) {
        #pragma unroll
        for (int j = 0; j < W_; ++j) r1[s - 4][j][lane] = acc[j];
    }
    if (lane == 0) {
        #pragma unroll
        for (int j = 0; j < W_; ++j) smask[s][j] = m[j];
    }
    __syncthreads();

    // Phase 1: waves 0..3 fold segments {s, s+4, s+8, s+12}; then publish
    // to r2 for the words they don't own (owner: wave 0 = words 0-4,
    // wave 1 = words 5-9).
    if (s < 4) {
        #pragma unroll
        for (int j = 0; j < W_; ++j) {
            float4 a = r1[s][j][lane];      // segment s+4
            float4 c = r1[s + 4][j][lane];  // segment s+8
            float4 d = r1[s + 8][j][lane];  // segment s+12
            max3_inplace(acc[j].x, a.x, c.x);
            max3_inplace(acc[j].y, a.y, c.y);
            max3_inplace(acc[j].z, a.z, c.z);
            max3_inplace(acc[j].w, a.w, c.w);
            acc[j].x = fmaxf(acc[j].x, d.x);
            acc[j].y = fmaxf(acc[j].y, d.y);
            acc[j].z = fmaxf(acc[j].z, d.z);
            acc[j].w = fmaxf(acc[j].w, d.w);
        }
        #pragma unroll
        for (int j = 0; j < W_; ++j) {
            const int o = (j < 5) ? 0 : 1;          // owner wave of word j
            if (s != o) {
                // contributors of word j in increasing wave order -> slot
                const int slot = (o == 0) ? (s - 1) : ((s == 0) ? 0 : (s - 1));
                r2[slot][j][lane] = acc[j];
            }
        }
    }
    __syncthreads();

    // Phase 2: owner waves finalize 5 words each.
    if (s < 2) {
        const int j0 = s * 5;
        #pragma unroll
        for (int jj = 0; jj < 5; ++jj) {
            const int j = j0 + jj;
            float4 r = acc[j];
            float4 a = r2[0][j][lane];
            float4 c = r2[1][j][lane];
            float4 d = r2[2][j][lane];
            max3_inplace(r.x, a.x, c.x);
            max3_inplace(r.y, a.y, c.y);
            max3_inplace(r.z, a.z, c.z);
            max3_inplace(r.w, a.w, c.w);
            r.x = fmaxf(r.x, d.x);
            r.y = fmaxf(r.y, d.y);
            r.z = fmaxf(r.z, d.z);
            r.w = fmaxf(r.w, d.w);

            unsigned int om = 0;
            #pragma unroll
            for (int seg = 0; seg < SEGS; ++seg) om |= smask[seg][j];

            if (om == 0u) {
                // Never taken for the fixed inputs; correct fallback =
                // global min over ALL of emb (reference min_value).
                const float4* x = (const float4*)emb;
                const int n4 = (B_ * LP_ * D_) / 4;
                float mn = __uint_as_float(0x7F800000u);  // +inf
                for (int i = lane; i < n4; i += 64) {
                    float4 vv = x[i];
                    mn = fminf(mn, fminf(fminf(vv.x, vv.y), fminf(vv.z, vv.w)));
                }
                #pragma unroll
                for (int off = 32; off > 0; off >>= 1)
                    mn = fminf(mn, __shfl_down(mn, off, 64));
                mn = __shfl(mn, 0, 64);
                r = make_float4(mn, mn, mn, mn);
            }

            float4* op = (float4*)out + (size_t)(b * LW_ + w0 + j) * D4_
                         + chunk * 64 + lane;
            *op = r;
        }
    }
}

extern "C" void kernel_launch(void* const* d_in, const int* in_sizes, int n_in,
                              void* d_out, int out_size, void* d_ws, size_t ws_size,
                              hipStream_t stream) {
    const float* emb = (const float*)d_in[0];
    const int*   p2w = (const int*)d_in[1];
    float*       out = (float*)d_out;
    (void)d_ws; (void)ws_size;

    word_max_scan<<<NBLK, 1024, SMEM_BYTES, stream>>>(emb, p2w, out);
}

// Round 6
// 67.778 us; speedup vs baseline: 1.5226x; 1.5226x over previous
//
#include <hip/hip_runtime.h>

// Problem shape (fixed by reference setup_inputs):
//   bert_emb:    [B=4, Lp=256, D=768] fp32
//   pieces2word: [B=4, Lw=200, Lp=256] int32 (0/1)
//   out:         [B=4, Lw=200, D=768] fp32
// out[b,w,d] = max over {p : mask[b,w,p]!=0} of emb[b,p,d], else global min(emb).
//
// R16 — R13 geometry + all-VALU bitwise gate (SALU elimination).
//  R15 post-mortem: 1024-thr + W=10 spilled acc to scratch (VGPR cap 44,
//  165 MB scratch writes, 53us/dispatch). Reverted to R13's proven geometry:
//  480 blocks x 512 threads, float4, W=5, PPS=32, 8 segments, 2 blk/CU
//  (16 waves/CU), single-pass 40 KB LDS merge.
//  Change vs R13: the gate. cndmask needed VCC per mask bit
//  (s_bitcmp1+s_cselect on the per-CU scalar pipe: 15 waves/CU x 320 SALU
//  ~ 2.0 us/CU, suspected partially critical after R12/R13 partial wins).
//  Replace with vector-only bitwise select:
//    vm[j]  = mask broadcast to VGPR (once per word, 5 v_mov total)
//    r      = v_bfe_i32(vm, bit, 1)      -> 0 or 0xFFFFFFFF  (1 VALU/bit)
//    sel    = v_bfi_b32(r, v, ninf)      -> v or -inf        (1 VALU/float)
//    acc    = v_max3(acc, sel0, sel1)
//  Per pair-word: 14 VALU + 0 SALU (was 12 VALU + 4 SALU). No VCC chains.
//  Decision rule: win confirms per-CU SALU criticality; regression ~+0.5us
//  falsifies it -> revert, attack latency next.
//  acc init = -inf bit-exact; empty-mask word -> global-min fallback.

#define B_  4
#define LP_ 256
#define LW_ 200
#define D_  768
#define D4_ (D_ / 4)              // 192 float4 per row
#define CHUNKS 3                  // 3 chunks x 256 floats (1 float4 per lane)
#define W_  5                     // words per block
#define WG_ (LW_ / W_)            // 40 word-groups
#define NBLK (B_ * CHUNKS * WG_)  // 480 blocks
#define SEGS 8                    // waves (piece segments) per block
#define PPS 32                    // pieces per segment

__device__ __forceinline__ void max3_inplace(float& d, float a, float b) {
    asm("v_max3_f32 %0, %1, %2, %3" : "=v"(d) : "v"(d), "v"(a), "v"(b));
}

__global__ __launch_bounds__(512) void word_max_scan(
    const float* __restrict__ emb, const int* __restrict__ p2w,
    float* __restrict__ out)
{
    const int blk   = blockIdx.x;
    const int wg    = blk % WG_;
    const int rest  = blk / WG_;
    const int chunk = rest % CHUNKS;
    const int b     = rest / CHUNKS;
    const int lane  = threadIdx.x & 63;
    const int s     = threadIdx.x >> 6;     // piece segment 0..7
    const int w0    = wg * W_;

    // Each wave ballots a 32-bit mask for its 32 pieces, per word.
    unsigned int m[W_];
    const int pc = s * PPS + (lane & 31);
    #pragma unroll
    for (int j = 0; j < W_; ++j) {
        const int* mrow = p2w + (b * LW_ + w0 + j) * LP_;
        m[j] = (unsigned int)__ballot((lane < 32) && (mrow[pc] != 0));
    }

    // VGPR-resident copies for the vector-pipe gate (one v_mov per word).
    int vm[W_];
    #pragma unroll
    for (int j = 0; j < W_; ++j)
        asm("v_mov_b32 %0, %1" : "=v"(vm[j]) : "s"(m[j]));
    float vninf;
    asm("v_mov_b32 %0, 0xff800000" : "=v"(vninf));

    const float ninf = __uint_as_float(0xFF800000u);
    float4 acc[W_];
    #pragma unroll
    for (int j = 0; j < W_; ++j) acc[j] = make_float4(ninf, ninf, ninf, ninf);

    // Wave's row stream: rows [32s, 32s+32), column = chunk*64 + lane (float4).
    const float4* rps = (const float4*)(emb + (size_t)b * LP_ * D_)
                        + chunk * 64 + lane + (size_t)(s * PPS) * D4_;

    #pragma unroll
    for (int g = 0; g < PPS; g += 8) {
        float4 v[8];
        #pragma unroll
        for (int k = 0; k < 8; ++k)
            v[k] = rps[(size_t)(g + k) * D4_];
        #pragma unroll
        for (int k = 0; k < 8; k += 2) {
            #pragma unroll
            for (int j = 0; j < W_; ++j) {
                // All-VALU gate: no VCC, no scalar pipe.
                int r0, r1;
                asm("v_bfe_i32 %0, %1, %2, 1"
                    : "=v"(r0) : "v"(vm[j]), "n"(g + k));
                asm("v_bfe_i32 %0, %1, %2, 1"
                    : "=v"(r1) : "v"(vm[j]), "n"(g + k + 1));
                float sx0, sy0, sz0, sw0, sx1, sy1, sz1, sw1;
                asm("v_bfi_b32 %0, %1, %2, %3"
                    : "=v"(sx0) : "v"(r0), "v"(v[k].x), "v"(vninf));
                asm("v_bfi_b32 %0, %1, %2, %3"
                    : "=v"(sy0) : "v"(r0), "v"(v[k].y), "v"(vninf));
                asm("v_bfi_b32 %0, %1, %2, %3"
                    : "=v"(sz0) : "v"(r0), "v"(v[k].z), "v"(vninf));
                asm("v_bfi_b32 %0, %1, %2, %3"
                    : "=v"(sw0) : "v"(r0), "v"(v[k].w), "v"(vninf));
                asm("v_bfi_b32 %0, %1, %2, %3"
                    : "=v"(sx1) : "v"(r1), "v"(v[k + 1].x), "v"(vninf));
                asm("v_bfi_b32 %0, %1, %2, %3"
                    : "=v"(sy1) : "v"(r1), "v"(v[k + 1].y), "v"(vninf));
                asm("v_bfi_b32 %0, %1, %2, %3"
                    : "=v"(sz1) : "v"(r1), "v"(v[k + 1].z), "v"(vninf));
                asm("v_bfi_b32 %0, %1, %2, %3"
                    : "=v"(sw1) : "v"(r1), "v"(v[k + 1].w), "v"(vninf));
                max3_inplace(acc[j].x, sx0, sx1);
                max3_inplace(acc[j].y, sy0, sy1);
                max3_inplace(acc[j].z, sz0, sz1);
                max3_inplace(acc[j].w, sw0, sw1);
            }
        }
    }

    // Merge the 8 segments via LDS (8 x 5 x 64 x 16B = 40 KB + masks).
    __shared__ float4 sacc[SEGS][W_][64];
    __shared__ unsigned int smask[SEGS][W_];
    #pragma unroll
    for (int j = 0; j < W_; ++j) sacc[s][j][lane] = acc[j];
    if (lane == 0) {
        #pragma unroll
        for (int j = 0; j < W_; ++j) smask[s][j] = m[j];
    }
    __syncthreads();

    // Wave j (< W_) finalizes word j.
    if (s < W_) {
        const int j = s;
        float4 r = sacc[0][j][lane];
        #pragma unroll
        for (int seg = 1; seg < SEGS; ++seg) {
            r.x = fmaxf(r.x, sacc[seg][j][lane].x);
            r.y = fmaxf(r.y, sacc[seg][j][lane].y);
            r.z = fmaxf(r.z, sacc[seg][j][lane].z);
            r.w = fmaxf(r.w, sacc[seg][j][lane].w);
        }
        unsigned int om = 0;
        #pragma unroll
        for (int seg = 0; seg < SEGS; ++seg) om |= smask[seg][j];

        if (om == 0u) {
            // Never taken for the fixed inputs; correct fallback = global
            // min over ALL of emb (reference min_value semantics).
            const float4* x = (const float4*)emb;
            const int n4 = (B_ * LP_ * D_) / 4;
            float mn = __uint_as_float(0x7F800000u);  // +inf
            for (int i = lane; i < n4; i += 64) {
                float4 vv = x[i];
                mn = fminf(mn, fminf(fminf(vv.x, vv.y), fminf(vv.z, vv.w)));
            }
            #pragma unroll
            for (int off = 32; off > 0; off >>= 1)
                mn = fminf(mn, __shfl_down(mn, off, 64));
            mn = __shfl(mn, 0, 64);
            r = make_float4(mn, mn, mn, mn);
        }

        float4* op = (float4*)out + (size_t)(b * LW_ + w0 + j) * D4_
                     + chunk * 64 + lane;
        *op = r;
    }
}

extern "C" void kernel_launch(void* const* d_in, const int* in_sizes, int n_in,
                              void* d_out, int out_size, void* d_ws, size_t ws_size,
                              hipStream_t stream) {
    const float* emb = (const float*)d_in[0];
    const int*   p2w = (const int*)d_in[1];
    float*       out = (float*)d_out;
    (void)d_ws; (void)ws_size;

    word_max_scan<<<NBLK, 512, 0, stream>>>(emb, p2w, out);
}

// Round 7
// 66.441 us; speedup vs baseline: 1.5532x; 1.0201x over previous
//
#include <hip/hip_runtime.h>

// Problem shape (fixed by reference setup_inputs):
//   bert_emb:    [B=4, Lp=256, D=768] fp32
//   pieces2word: [B=4, Lw=200, Lp=256] int32 (0/1)
//   out:         [B=4, Lw=200, D=768] fp32
// out[b,w,d] = max over {p : mask[b,w,p]!=0} of emb[b,p,d], else global min(emb).
//
// R17 — R13 + explicit two-buffer software pipeline (ONLY change).
//  R16 post-mortem: bfe/bfi all-VALU gate regressed +1.8us -> SALU was never
//  the co-bottleneck; R13's residual ~3-5us slack re-attributed to per-wave
//  load->wait->compute serialization (also retro-explains R14: half the
//  waves, double the exposure, +2.2us).
//  Fix: double-buffer the 8-row load batches so merge of batch g overlaps
//  the in-flight loads of batch g+1:
//    load va(0); load vb(8); merge va | load va(16); merge vb | load vb(24);
//    merge va; merge vb
//  VGPR ~100 (va+vb 64, acc 20) < 128 cap at 4 waves/SIMD.
//  Geometry & gate identical to R13 (best, 65.95): 480 blocks x 512 thr,
//  float4, W=5, PPS=32, cndmask gate + v_max3 pair-merge (1.5 VALU/elem),
//  single-pass 40KB LDS merge.
//  acc init = -inf bit-exact; empty-mask word -> global-min fallback.

#define B_  4
#define LP_ 256
#define LW_ 200
#define D_  768
#define D4_ (D_ / 4)              // 192 float4 per row
#define CHUNKS 3                  // 3 chunks x 256 floats (1 float4 per lane)
#define W_  5                     // words per block
#define WG_ (LW_ / W_)            // 40 word-groups
#define NBLK (B_ * CHUNKS * WG_)  // 480 blocks
#define SEGS 8                    // waves (piece segments) per block
#define PPS 32                    // pieces per segment

__device__ __forceinline__ void max3_inplace(float& d, float a, float b) {
    asm("v_max3_f32 %0, %1, %2, %3" : "=v"(d) : "v"(d), "v"(a), "v"(b));
}

__global__ __launch_bounds__(512) void word_max_scan(
    const float* __restrict__ emb, const int* __restrict__ p2w,
    float* __restrict__ out)
{
    const int blk   = blockIdx.x;
    const int wg    = blk % WG_;
    const int rest  = blk / WG_;
    const int chunk = rest % CHUNKS;
    const int b     = rest / CHUNKS;
    const int lane  = threadIdx.x & 63;
    const int s     = threadIdx.x >> 6;     // piece segment 0..7
    const int w0    = wg * W_;

    // Each wave ballots a 32-bit mask for its 32 pieces, per word.
    unsigned int m[W_];
    const int pc = s * PPS + (lane & 31);
    #pragma unroll
    for (int j = 0; j < W_; ++j) {
        const int* mrow = p2w + (b * LW_ + w0 + j) * LP_;
        m[j] = (unsigned int)__ballot((lane < 32) && (mrow[pc] != 0));
    }

    const float ninf = __uint_as_float(0xFF800000u);
    float4 acc[W_];
    #pragma unroll
    for (int j = 0; j < W_; ++j) acc[j] = make_float4(ninf, ninf, ninf, ninf);

    // Wave's row stream: rows [32s, 32s+32), column = chunk*64 + lane (float4).
    const float4* rps = (const float4*)(emb + (size_t)b * LP_ * D_)
                        + chunk * 64 + lane + (size_t)(s * PPS) * D4_;

    // Gated pair-merge of rows (g+k, g+k+1) for all words; g compile-time.
#define MERGE8(vv, g)                                                        \
    do {                                                                     \
        _Pragma("unroll")                                                    \
        for (int k = 0; k < 8; k += 2) {                                     \
            _Pragma("unroll")                                                \
            for (int j = 0; j < W_; ++j) {                                   \
                const bool b0 = (m[j] >> ((g) + k))     & 1u;  /* uniform */ \
                const bool b1 = (m[j] >> ((g) + k + 1)) & 1u;  /* uniform */ \
                float sx0 = b0 ? vv[k].x     : ninf;                         \
                float sy0 = b0 ? vv[k].y     : ninf;                         \
                float sz0 = b0 ? vv[k].z     : ninf;                         \
                float sw0 = b0 ? vv[k].w     : ninf;                         \
                float sx1 = b1 ? vv[k + 1].x : ninf;                         \
                float sy1 = b1 ? vv[k + 1].y : ninf;                         \
                float sz1 = b1 ? vv[k + 1].z : ninf;                         \
                float sw1 = b1 ? vv[k + 1].w : ninf;                         \
                max3_inplace(acc[j].x, sx0, sx1);                            \
                max3_inplace(acc[j].y, sy0, sy1);                            \
                max3_inplace(acc[j].z, sz0, sz1);                            \
                max3_inplace(acc[j].w, sw0, sw1);                            \
            }                                                                \
        }                                                                    \
    } while (0)

#define LOAD8(vv, g)                                                         \
    do {                                                                     \
        _Pragma("unroll")                                                    \
        for (int k = 0; k < 8; ++k)                                          \
            vv[k] = rps[(size_t)((g) + k) * D4_];                            \
    } while (0)

    float4 va[8], vb[8];
    LOAD8(va, 0);        // prologue
    LOAD8(vb, 8);        // batch 1 in flight...
    MERGE8(va, 0);       // ...while merging batch 0
    LOAD8(va, 16);       // batch 2 in flight...
    MERGE8(vb, 8);       // ...while merging batch 1
    LOAD8(vb, 24);       // batch 3 in flight...
    MERGE8(va, 16);      // ...while merging batch 2
    MERGE8(vb, 24);      // drain

#undef MERGE8
#undef LOAD8

    // Merge the 8 segments via LDS (8 x 5 x 64 x 16B = 40 KB + masks).
    __shared__ float4 sacc[SEGS][W_][64];
    __shared__ unsigned int smask[SEGS][W_];
    #pragma unroll
    for (int j = 0; j < W_; ++j) sacc[s][j][lane] = acc[j];
    if (lane == 0) {
        #pragma unroll
        for (int j = 0; j < W_; ++j) smask[s][j] = m[j];
    }
    __syncthreads();

    // Wave j (< W_) finalizes word j.
    if (s < W_) {
        const int j = s;
        float4 r = sacc[0][j][lane];
        #pragma unroll
        for (int seg = 1; seg < SEGS; ++seg) {
            r.x = fmaxf(r.x, sacc[seg][j][lane].x);
            r.y = fmaxf(r.y, sacc[seg][j][lane].y);
            r.z = fmaxf(r.z, sacc[seg][j][lane].z);
            r.w = fmaxf(r.w, sacc[seg][j][lane].w);
        }
        unsigned int om = 0;
        #pragma unroll
        for (int seg = 0; seg < SEGS; ++seg) om |= smask[seg][j];

        if (om == 0u) {
            // Never taken for the fixed inputs; correct fallback = global
            // min over ALL of emb (reference min_value semantics).
            const float4* x = (const float4*)emb;
            const int n4 = (B_ * LP_ * D_) / 4;
            float mn = __uint_as_float(0x7F800000u);  // +inf
            for (int i = lane; i < n4; i += 64) {
                float4 vv = x[i];
                mn = fminf(mn, fminf(fminf(vv.x, vv.y), fminf(vv.z, vv.w)));
            }
            #pragma unroll
            for (int off = 32; off > 0; off >>= 1)
                mn = fminf(mn, __shfl_down(mn, off, 64));
            mn = __shfl(mn, 0, 64);
            r = make_float4(mn, mn, mn, mn);
        }

        float4* op = (float4*)out + (size_t)(b * LW_ + w0 + j) * D4_
                     + chunk * 64 + lane;
        *op = r;
    }
}

extern "C" void kernel_launch(void* const* d_in, const int* in_sizes, int n_in,
                              void* d_out, int out_size, void* d_ws, size_t ws_size,
                              hipStream_t stream) {
    const float* emb = (const float*)d_in[0];
    const int*   p2w = (const int*)d_in[1];
    float*       out = (float*)d_out;
    (void)d_ws; (void)ws_size;

    word_max_scan<<<NBLK, 512, 0, stream>>>(emb, p2w, out);
}

// Round 8
// 64.985 us; speedup vs baseline: 1.5880x; 1.0224x over previous
//
#include <hip/hip_runtime.h>

// Problem shape (fixed by reference setup_inputs):
//   bert_emb:    [B=4, Lp=256, D=768] fp32
//   pieces2word: [B=4, Lw=200, Lp=256] int32 (0/1)
//   out:         [B=4, Lw=200, D=768] fp32
// out[b,w,d] = max over {p : mask[b,w,p]!=0} of emb[b,p,d], else global min(emb).
//
// R18 — R13 (best, 65.95) + prologue/epilogue micro-bundle.
//  Ledger: R14/R15 (L2-stream cut) fail via occupancy/VGPR; two-kernel split
//  arithmetic is net-negative; R16 (SALU gate) falsified; R17 (explicit
//  pipeline) neutral -> compiler already pipelines. Remaining addressable
//  cost is the prologue/epilogue tail:
//   1. Packed ballots: lanes 0-31 test word j, lanes 32-63 word j+1 in ONE
//      64-bit ballot -> 3 p2w loads + 3 ballots (was 5+5, with upper lanes
//      issuing duplicate loads).
//   2. smask LDS round-trip removed: finalize wave recomputes the
//      empty-word check from p2w directly (1 dwordx4 + 1 ballot) instead of
//      8x5 lane-0 LDS writes + 40 scalar LDS reads.
//  Main loop, geometry, gate identical to R13: 480 blocks x 512 thr,
//  float4, W=5, PPS=32, unroll-8 batches, cndmask gate + v_max3 pair-merge
//  (1.5 VALU/elem), single-pass 40KB LDS merge.
//  acc init = -inf bit-exact; empty-mask word -> global-min fallback.

#define B_  4
#define LP_ 256
#define LW_ 200
#define D_  768
#define D4_ (D_ / 4)              // 192 float4 per row
#define CHUNKS 3                  // 3 chunks x 256 floats (1 float4 per lane)
#define W_  5                     // words per block
#define WG_ (LW_ / W_)            // 40 word-groups
#define NBLK (B_ * CHUNKS * WG_)  // 480 blocks
#define SEGS 8                    // waves (piece segments) per block
#define PPS 32                    // pieces per segment

__device__ __forceinline__ void max3_inplace(float& d, float a, float b) {
    asm("v_max3_f32 %0, %1, %2, %3" : "=v"(d) : "v"(d), "v"(a), "v"(b));
}

__global__ __launch_bounds__(512) void word_max_scan(
    const float* __restrict__ emb, const int* __restrict__ p2w,
    float* __restrict__ out)
{
    const int blk   = blockIdx.x;
    const int wg    = blk % WG_;
    const int rest  = blk / WG_;
    const int chunk = rest % CHUNKS;
    const int b     = rest / CHUNKS;
    const int lane  = threadIdx.x & 63;
    const int s     = threadIdx.x >> 6;     // piece segment 0..7
    const int w0    = wg * W_;

    // Packed ballots: one 64-bit ballot covers TWO words (lo lanes -> word
    // jp, hi lanes -> word jp+1); piece index = s*PPS + (lane&31) for both.
    unsigned int m[W_];
    const int pc = s * PPS + (lane & 31);
    #pragma unroll
    for (int jp = 0; jp < W_; jp += 2) {
        const int jhi = (jp + 1 < W_) ? (jp + 1) : jp;  // last: both halves jp
        const int j   = (lane >= 32) ? jhi : jp;
        const int* mrow = p2w + (b * LW_ + w0 + j) * LP_;
        unsigned long long bal = __ballot(mrow[pc] != 0);
        m[jp] = (unsigned int)bal;
        if (jp + 1 < W_) m[jp + 1] = (unsigned int)(bal >> 32);
    }

    const float ninf = __uint_as_float(0xFF800000u);
    float4 acc[W_];
    #pragma unroll
    for (int j = 0; j < W_; ++j) acc[j] = make_float4(ninf, ninf, ninf, ninf);

    // Wave's row stream: rows [32s, 32s+32), column = chunk*64 + lane (float4).
    const float4* rps = (const float4*)(emb + (size_t)b * LP_ * D_)
                        + chunk * 64 + lane + (size_t)(s * PPS) * D4_;

    #pragma unroll
    for (int g = 0; g < PPS; g += 8) {
        float4 v[8];
        #pragma unroll
        for (int k = 0; k < 8; ++k)
            v[k] = rps[(size_t)(g + k) * D4_];
        #pragma unroll
        for (int k = 0; k < 8; k += 2) {
            #pragma unroll
            for (int j = 0; j < W_; ++j) {
                const bool b0 = (m[j] >> (g + k))     & 1u;  // uniform
                const bool b1 = (m[j] >> (g + k + 1)) & 1u;  // uniform
                // One VCC per bit gates FOUR cndmasks (amortized SALU).
                float sx0 = b0 ? v[k].x     : ninf;
                float sy0 = b0 ? v[k].y     : ninf;
                float sz0 = b0 ? v[k].z     : ninf;
                float sw0 = b0 ? v[k].w     : ninf;
                float sx1 = b1 ? v[k + 1].x : ninf;
                float sy1 = b1 ? v[k + 1].y : ninf;
                float sz1 = b1 ? v[k + 1].z : ninf;
                float sw1 = b1 ? v[k + 1].w : ninf;
                max3_inplace(acc[j].x, sx0, sx1);
                max3_inplace(acc[j].y, sy0, sy1);
                max3_inplace(acc[j].z, sz0, sz1);
                max3_inplace(acc[j].w, sw0, sw1);
            }
        }
    }

    // Merge the 8 segments via LDS (8 x 5 x 64 x 16B = 40 KB).
    __shared__ float4 sacc[SEGS][W_][64];
    #pragma unroll
    for (int j = 0; j < W_; ++j) sacc[s][j][lane] = acc[j];
    __syncthreads();

    // Wave j (< W_) finalizes word j.
    if (s < W_) {
        const int j = s;
        float4 r = sacc[0][j][lane];
        #pragma unroll
        for (int seg = 1; seg < SEGS; ++seg) {
            r.x = fmaxf(r.x, sacc[seg][j][lane].x);
            r.y = fmaxf(r.y, sacc[seg][j][lane].y);
            r.z = fmaxf(r.z, sacc[seg][j][lane].z);
            r.w = fmaxf(r.w, sacc[seg][j][lane].w);
        }

        // Empty-word check recomputed from p2w directly (no smask LDS):
        // 64 lanes x int4 covers the full 256-piece row.
        const int4 mv = ((const int4*)(p2w + (b * LW_ + w0 + j) * LP_))[lane];
        const unsigned long long nz =
            __ballot((mv.x | mv.y | mv.z | mv.w) != 0);

        if (nz == 0ull) {
            // Never taken for the fixed inputs; correct fallback = global
            // min over ALL of emb (reference min_value semantics).
            const float4* x = (const float4*)emb;
            const int n4 = (B_ * LP_ * D_) / 4;
            float mn = __uint_as_float(0x7F800000u);  // +inf
            for (int i = lane; i < n4; i += 64) {
                float4 vv = x[i];
                mn = fminf(mn, fminf(fminf(vv.x, vv.y), fminf(vv.z, vv.w)));
            }
            #pragma unroll
            for (int off = 32; off > 0; off >>= 1)
                mn = fminf(mn, __shfl_down(mn, off, 64));
            mn = __shfl(mn, 0, 64);
            r = make_float4(mn, mn, mn, mn);
        }

        float4* op = (float4*)out + (size_t)(b * LW_ + w0 + j) * D4_
                     + chunk * 64 + lane;
        *op = r;
    }
}

extern "C" void kernel_launch(void* const* d_in, const int* in_sizes, int n_in,
                              void* d_out, int out_size, void* d_ws, size_t ws_size,
                              hipStream_t stream) {
    const float* emb = (const float*)d_in[0];
    const int*   p2w = (const int*)d_in[1];
    float*       out = (float*)d_out;
    (void)d_ws; (void)ws_size;

    word_max_scan<<<NBLK, 512, 0, stream>>>(emb, p2w, out);
}

// Round 9
// 64.493 us; speedup vs baseline: 1.6001x; 1.0076x over previous
//
#include <hip/hip_runtime.h>

// Problem shape (fixed by reference setup_inputs):
//   bert_emb:    [B=4, Lp=256, D=768] fp32
//   pieces2word: [B=4, Lw=200, Lp=256] int32 (0/1)
//   out:         [B=4, Lw=200, D=768] fp32
// out[b,w,d] = max over {p : mask[b,w,p]!=0} of emb[b,p,d], else global min(emb).
//
// R19 — R18 (best, 64.98) + XCD-locality block swizzle (ONLY change).
//  Theory: cold-start HBM ramp. 40 consecutive blocks share one 256KB emb
//  slice (b,chunk); default round-robin dispatch (XCD = blk%8, m09) puts
//  each slice in 8 different L2s -> ~24MB HBM fetched in the first us of
//  the kernel (latency-bound ramp not in the steady-state issue model).
//  Swizzle: virt = (blk&7)*60 + (blk>>3)   (bijective, 480 = 8*60)
//  -> each XCD owns 60 slice-contiguous blocks (1.5 slices); per-slice L2
//  copies drop 8 -> <=2 (~5MB HBM). CU balance preserved exactly
//  (60 blocks / 32 CUs per XCD = 1.875, same as global 480/256).
//  Worst case (mapping assumption wrong): relabeling ~ neutral.
//  Everything else identical to R18: 480 blocks x 512 thr, float4, W=5,
//  PPS=32, packed ballots, cndmask gate + v_max3 pair-merge (1.5 VALU/elem),
//  single-pass 40KB LDS merge (no smask round-trip), epilogue om recompute.
//  acc init = -inf bit-exact; empty-mask word -> global-min fallback.

#define B_  4
#define LP_ 256
#define LW_ 200
#define D_  768
#define D4_ (D_ / 4)              // 192 float4 per row
#define CHUNKS 3                  // 3 chunks x 256 floats (1 float4 per lane)
#define W_  5                     // words per block
#define WG_ (LW_ / W_)            // 40 word-groups
#define NBLK (B_ * CHUNKS * WG_)  // 480 blocks = 8 XCDs x 60
#define SEGS 8                    // waves (piece segments) per block
#define PPS 32                    // pieces per segment

__device__ __forceinline__ void max3_inplace(float& d, float a, float b) {
    asm("v_max3_f32 %0, %1, %2, %3" : "=v"(d) : "v"(d), "v"(a), "v"(b));
}

__global__ __launch_bounds__(512) void word_max_scan(
    const float* __restrict__ emb, const int* __restrict__ p2w,
    float* __restrict__ out)
{
    // XCD-locality swizzle: hw XCD = blockIdx.x % 8 (round-robin, m09).
    // virt enumerates blocks slice-major; each XCD gets 60 consecutive
    // virt ids = ~1.5 emb slices -> slice lives in <=2 XCD L2s.
    const int blk   = (blockIdx.x & 7) * (NBLK / 8) + (blockIdx.x >> 3);
    const int wg    = blk % WG_;
    const int rest  = blk / WG_;
    const int chunk = rest % CHUNKS;
    const int b     = rest / CHUNKS;
    const int lane  = threadIdx.x & 63;
    const int s     = threadIdx.x >> 6;     // piece segment 0..7
    const int w0    = wg * W_;

    // Packed ballots: one 64-bit ballot covers TWO words (lo lanes -> word
    // jp, hi lanes -> word jp+1); piece index = s*PPS + (lane&31) for both.
    unsigned int m[W_];
    const int pc = s * PPS + (lane & 31);
    #pragma unroll
    for (int jp = 0; jp < W_; jp += 2) {
        const int jhi = (jp + 1 < W_) ? (jp + 1) : jp;  // last: both halves jp
        const int j   = (lane >= 32) ? jhi : jp;
        const int* mrow = p2w + (b * LW_ + w0 + j) * LP_;
        unsigned long long bal = __ballot(mrow[pc] != 0);
        m[jp] = (unsigned int)bal;
        if (jp + 1 < W_) m[jp + 1] = (unsigned int)(bal >> 32);
    }

    const float ninf = __uint_as_float(0xFF800000u);
    float4 acc[W_];
    #pragma unroll
    for (int j = 0; j < W_; ++j) acc[j] = make_float4(ninf, ninf, ninf, ninf);

    // Wave's row stream: rows [32s, 32s+32), column = chunk*64 + lane (float4).
    const float4* rps = (const float4*)(emb + (size_t)b * LP_ * D_)
                        + chunk * 64 + lane + (size_t)(s * PPS) * D4_;

    #pragma unroll
    for (int g = 0; g < PPS; g += 8) {
        float4 v[8];
        #pragma unroll
        for (int k = 0; k < 8; ++k)
            v[k] = rps[(size_t)(g + k) * D4_];
        #pragma unroll
        for (int k = 0; k < 8; k += 2) {
            #pragma unroll
            for (int j = 0; j < W_; ++j) {
                const bool b0 = (m[j] >> (g + k))     & 1u;  // uniform
                const bool b1 = (m[j] >> (g + k + 1)) & 1u;  // uniform
                // One VCC per bit gates FOUR cndmasks (amortized SALU).
                float sx0 = b0 ? v[k].x     : ninf;
                float sy0 = b0 ? v[k].y     : ninf;
                float sz0 = b0 ? v[k].z     : ninf;
                float sw0 = b0 ? v[k].w     : ninf;
                float sx1 = b1 ? v[k + 1].x : ninf;
                float sy1 = b1 ? v[k + 1].y : ninf;
                float sz1 = b1 ? v[k + 1].z : ninf;
                float sw1 = b1 ? v[k + 1].w : ninf;
                max3_inplace(acc[j].x, sx0, sx1);
                max3_inplace(acc[j].y, sy0, sy1);
                max3_inplace(acc[j].z, sz0, sz1);
                max3_inplace(acc[j].w, sw0, sw1);
            }
        }
    }

    // Merge the 8 segments via LDS (8 x 5 x 64 x 16B = 40 KB).
    __shared__ float4 sacc[SEGS][W_][64];
    #pragma unroll
    for (int j = 0; j < W_; ++j) sacc[s][j][lane] = acc[j];
    __syncthreads();

    // Wave j (< W_) finalizes word j.
    if (s < W_) {
        const int j = s;
        float4 r = sacc[0][j][lane];
        #pragma unroll
        for (int seg = 1; seg < SEGS; ++seg) {
            r.x = fmaxf(r.x, sacc[seg][j][lane].x);
            r.y = fmaxf(r.y, sacc[seg][j][lane].y);
            r.z = fmaxf(r.z, sacc[seg][j][lane].z);
            r.w = fmaxf(r.w, sacc[seg][j][lane].w);
        }

        // Empty-word check recomputed from p2w directly (no smask LDS):
        // 64 lanes x int4 covers the full 256-piece row.
        const int4 mv = ((const int4*)(p2w + (b * LW_ + w0 + j) * LP_))[lane];
        const unsigned long long nz =
            __ballot((mv.x | mv.y | mv.z | mv.w) != 0);

        if (nz == 0ull) {
            // Never taken for the fixed inputs; correct fallback = global
            // min over ALL of emb (reference min_value semantics).
            const float4* x = (const float4*)emb;
            const int n4 = (B_ * LP_ * D_) / 4;
            float mn = __uint_as_float(0x7F800000u);  // +inf
            for (int i = lane; i < n4; i += 64) {
                float4 vv = x[i];
                mn = fminf(mn, fminf(fminf(vv.x, vv.y), fminf(vv.z, vv.w)));
            }
            #pragma unroll
            for (int off = 32; off > 0; off >>= 1)
                mn = fminf(mn, __shfl_down(mn, off, 64));
            mn = __shfl(mn, 0, 64);
            r = make_float4(mn, mn, mn, mn);
        }

        float4* op = (float4*)out + (size_t)(b * LW_ + w0 + j) * D4_
                     + chunk * 64 + lane;
        *op = r;
    }
}

extern "C" void kernel_launch(void* const* d_in, const int* in_sizes, int n_in,
                              void* d_out, int out_size, void* d_ws, size_t ws_size,
                              hipStream_t stream) {
    const float* emb = (const float*)d_in[0];
    const int*   p2w = (const int*)d_in[1];
    float*       out = (float*)d_out;
    (void)d_ws; (void)ws_size;

    word_max_scan<<<NBLK, 512, 0, stream>>>(emb, p2w, out);
}

// Round 11
// 64.034 us; speedup vs baseline: 1.6116x; 1.0072x over previous
//
#include <hip/hip_runtime.h>

// Problem shape (fixed by reference setup_inputs):
//   bert_emb:    [B=4, Lp=256, D=768] fp32
//   pieces2word: [B=4, Lw=200, Lp=256] int32 (0/1)
//   out:         [B=4, Lw=200, D=768] fp32
// out[b,w,d] = max over {p : mask[b,w,p]!=0} of emb[b,p,d], else global min(emb).
//
// R21 — R20 resubmit with compile fix (ONLY delta vs R20: nontemporal store
// goes through a clang native vector type; __builtin_nontemporal_store
// rejects HIP_vector_type float4).
//  R20 changes under test (vs R19, best 64.49):
//  (a) empty-word check hoisted ABOVE the main loop: p2w row is cache-hot
//      after the ballot phase; ~200cy latency hides under the merge loop
//      instead of sitting serially after __syncthreads.
//  (b) out stores via nontemporal dwordx4: out is write-once (2.4 MB);
//      default write-allocate pollutes the L2 slices holding hot emb.
//  Ledger: confirmed = v_max3 merge (R12), float4 amortization (R13),
//  tail trim (R18), XCD swizzle (R19). Falsified = branch-skip (R11),
//  L2-cut-via-geometry (R14/R15), SALU gate (R16), explicit pipeline (R17).
//  Geometry: 480 blocks x 512 thr, float4, W=5, PPS=32, packed ballots,
//  XCD swizzle virt=(blk&7)*60+(blk>>3), cndmask gate + v_max3 pair-merge
//  (1.5 VALU/elem), single-pass 40KB LDS merge.
//  acc init = -inf bit-exact; empty-mask word -> global-min fallback.

#define B_  4
#define LP_ 256
#define LW_ 200
#define D_  768
#define D4_ (D_ / 4)              // 192 float4 per row
#define CHUNKS 3                  // 3 chunks x 256 floats (1 float4 per lane)
#define W_  5                     // words per block
#define WG_ (LW_ / W_)            // 40 word-groups
#define NBLK (B_ * CHUNKS * WG_)  // 480 blocks = 8 XCDs x 60
#define SEGS 8                    // waves (piece segments) per block
#define PPS 32                    // pieces per segment

typedef float v4f __attribute__((ext_vector_type(4)));

__device__ __forceinline__ void max3_inplace(float& d, float a, float b) {
    asm("v_max3_f32 %0, %1, %2, %3" : "=v"(d) : "v"(d), "v"(a), "v"(b));
}

__global__ __launch_bounds__(512) void word_max_scan(
    const float* __restrict__ emb, const int* __restrict__ p2w,
    float* __restrict__ out)
{
    // XCD-locality swizzle: hw XCD = blockIdx.x % 8 (round-robin, m09).
    const int blk   = (blockIdx.x & 7) * (NBLK / 8) + (blockIdx.x >> 3);
    const int wg    = blk % WG_;
    const int rest  = blk / WG_;
    const int chunk = rest % CHUNKS;
    const int b     = rest / CHUNKS;
    const int lane  = threadIdx.x & 63;
    const int s     = threadIdx.x >> 6;     // piece segment 0..7
    const int w0    = wg * W_;

    // Packed ballots: one 64-bit ballot covers TWO words (lo lanes -> word
    // jp, hi lanes -> word jp+1); piece index = s*PPS + (lane&31) for both.
    unsigned int m[W_];
    const int pc = s * PPS + (lane & 31);
    #pragma unroll
    for (int jp = 0; jp < W_; jp += 2) {
        const int jhi = (jp + 1 < W_) ? (jp + 1) : jp;  // last: both halves jp
        const int j   = (lane >= 32) ? jhi : jp;
        const int* mrow = p2w + (b * LW_ + w0 + j) * LP_;
        unsigned long long bal = __ballot(mrow[pc] != 0);
        m[jp] = (unsigned int)bal;
        if (jp + 1 < W_) m[jp + 1] = (unsigned int)(bal >> 32);
    }

    // (a) Early empty-word check for the finalize waves (s < W_): the p2w
    // row is cache-hot from the ballot phase; latency hides under the main
    // loop. Carried as one wave-uniform bool to the epilogue.
    bool word_empty = false;
    if (s < W_) {
        const int4 mv =
            ((const int4*)(p2w + (b * LW_ + w0 + s) * LP_))[lane];
        word_empty =
            (__ballot((mv.x | mv.y | mv.z | mv.w) != 0) == 0ull);
    }

    const float ninf = __uint_as_float(0xFF800000u);
    float4 acc[W_];
    #pragma unroll
    for (int j = 0; j < W_; ++j) acc[j] = make_float4(ninf, ninf, ninf, ninf);

    // Wave's row stream: rows [32s, 32s+32), column = chunk*64 + lane (float4).
    const float4* rps = (const float4*)(emb + (size_t)b * LP_ * D_)
                        + chunk * 64 + lane + (size_t)(s * PPS) * D4_;

    #pragma unroll
    for (int g = 0; g < PPS; g += 8) {
        float4 v[8];
        #pragma unroll
        for (int k = 0; k < 8; ++k)
            v[k] = rps[(size_t)(g + k) * D4_];
        #pragma unroll
        for (int k = 0; k < 8; k += 2) {
            #pragma unroll
            for (int j = 0; j < W_; ++j) {
                const bool b0 = (m[j] >> (g + k))     & 1u;  // uniform
                const bool b1 = (m[j] >> (g + k + 1)) & 1u;  // uniform
                // One VCC per bit gates FOUR cndmasks (amortized SALU).
                float sx0 = b0 ? v[k].x     : ninf;
                float sy0 = b0 ? v[k].y     : ninf;
                float sz0 = b0 ? v[k].z     : ninf;
                float sw0 = b0 ? v[k].w     : ninf;
                float sx1 = b1 ? v[k + 1].x : ninf;
                float sy1 = b1 ? v[k + 1].y : ninf;
                float sz1 = b1 ? v[k + 1].z : ninf;
                float sw1 = b1 ? v[k + 1].w : ninf;
                max3_inplace(acc[j].x, sx0, sx1);
                max3_inplace(acc[j].y, sy0, sy1);
                max3_inplace(acc[j].z, sz0, sz1);
                max3_inplace(acc[j].w, sw0, sw1);
            }
        }
    }

    // Merge the 8 segments via LDS (8 x 5 x 64 x 16B = 40 KB).
    __shared__ float4 sacc[SEGS][W_][64];
    #pragma unroll
    for (int j = 0; j < W_; ++j) sacc[s][j][lane] = acc[j];
    __syncthreads();

    // Wave j (< W_) finalizes word j.
    if (s < W_) {
        const int j = s;
        float4 r = sacc[0][j][lane];
        #pragma unroll
        for (int seg = 1; seg < SEGS; ++seg) {
            r.x = fmaxf(r.x, sacc[seg][j][lane].x);
            r.y = fmaxf(r.y, sacc[seg][j][lane].y);
            r.z = fmaxf(r.z, sacc[seg][j][lane].z);
            r.w = fmaxf(r.w, sacc[seg][j][lane].w);
        }

        if (word_empty) {
            // Never taken for the fixed inputs; correct fallback = global
            // min over ALL of emb (reference min_value semantics).
            const float4* x = (const float4*)emb;
            const int n4 = (B_ * LP_ * D_) / 4;
            float mn = __uint_as_float(0x7F800000u);  // +inf
            for (int i = lane; i < n4; i += 64) {
                float4 vv = x[i];
                mn = fminf(mn, fminf(fminf(vv.x, vv.y), fminf(vv.z, vv.w)));
            }
            #pragma unroll
            for (int off = 32; off > 0; off >>= 1)
                mn = fminf(mn, __shfl_down(mn, off, 64));
            mn = __shfl(mn, 0, 64);
            r = make_float4(mn, mn, mn, mn);
        }

        // (b) Write-once output: nontemporal dwordx4 (clang native vector
        // type; __builtin_nontemporal_store rejects HIP_vector_type).
        v4f* op = (v4f*)((float4*)out + (size_t)(b * LW_ + w0 + j) * D4_
                         + chunk * 64 + lane);
        v4f rv;
        rv.x = r.x; rv.y = r.y; rv.z = r.z; rv.w = r.w;
        __builtin_nontemporal_store(rv, op);
    }
}

extern "C" void kernel_launch(void* const* d_in, const int* in_sizes, int n_in,
                              void* d_out, int out_size, void* d_ws, size_t ws_size,
                              hipStream_t stream) {
    const float* emb = (const float*)d_in[0];
    const int*   p2w = (const int*)d_in[1];
    float*       out = (float*)d_out;
    (void)d_ws; (void)ws_size;

    word_max_scan<<<NBLK, 512, 0, stream>>>(emb, p2w, out);
}